// Round 1
// baseline (39.833 us; speedup 1.0000x reference)
//
#include <hip/hip_runtime.h>
#include <math.h>

// MorphLayer: out = exp(maxplus(p1,k1)) - exp(maxplus(p1,k2))
//           - exp(maxplus(p2,k1)) + exp(maxplus(p2,k2)) + bias
// p1 = im2col(log(max(x,1e-12))), p2 = im2col(log(max(-x,1e-12)))
// x: (16,3,66,66) f32, k1/k2: (27,32) f32, bias: (32,), out: (16,32,64,64) f32

#define BB 16
#define CC 3
#define HH 66
#define WW 66
#define HO 64
#define WO 64
#define FF 32
#define KK 27
#define FPG 8              // filters per block
#define FG (FF / FPG)      // 4 filter groups
#define LOGMIN -27.631021115928547f  // logf(1e-12f)

__global__ __launch_bounds__(256, 4)
void morph_kernel(const float* __restrict__ x,
                  const float* __restrict__ k1,
                  const float* __restrict__ k2,
                  const float* __restrict__ bias,
                  float* __restrict__ out) {
    const int tid = threadIdx.x;
    const int wo = tid & 63;        // 0..63
    const int r  = tid >> 6;        // 0..3 (row within block)
    int bid = blockIdx.x;
    const int fg = bid & (FG - 1);  bid >>= 2;   // filter group 0..3
    const int rg = bid & 15;        bid >>= 4;   // row group 0..15
    const int b  = bid;                          // batch 0..15
    const int ho = rg * 4 + r;

    // Load 3x3x3 neighborhood once; one log per element + two selects.
    float a1[KK], a2[KK];
    const float* xb = x + ((size_t)b * CC * HH * WW);
    #pragma unroll
    for (int c = 0; c < CC; ++c) {
        #pragma unroll
        for (int di = 0; di < 3; ++di) {
            #pragma unroll
            for (int dj = 0; dj < 3; ++dj) {
                float v = xb[(c * HH + (ho + di)) * WW + (wo + dj)];
                float l = __logf(fabsf(v));
                const int k = c * 9 + di * 3 + dj;
                a1[k] = (v >=  1e-12f) ? l : LOGMIN;  // log(max(x,1e-12))
                a2[k] = (v <= -1e-12f) ? l : LOGMIN;  // log(max(-x,1e-12))
            }
        }
    }

    const int f0 = fg * FPG;
    #pragma unroll
    for (int ff = 0; ff < FPG; ++ff) {
        const int f = f0 + ff;
        float m11 = -3.4e38f, m12 = -3.4e38f, m21 = -3.4e38f, m22 = -3.4e38f;
        // k-loop fully unrolled; w1/w2 are wave-uniform -> scalar loads.
        #pragma unroll
        for (int k = 0; k < KK; ++k) {
            const float w1 = k1[k * FF + f];
            const float w2 = k2[k * FF + f];
            m11 = fmaxf(m11, a1[k] + w1);
            m12 = fmaxf(m12, a1[k] + w2);
            m21 = fmaxf(m21, a2[k] + w1);
            m22 = fmaxf(m22, a2[k] + w2);
        }
        const float res = __expf(m11) - __expf(m12) - __expf(m21) + __expf(m22)
                        + bias[f];
        out[(((size_t)b * FF + f) * HO + ho) * WO + wo] = res;
    }
}

extern "C" void kernel_launch(void* const* d_in, const int* in_sizes, int n_in,
                              void* d_out, int out_size, void* d_ws, size_t ws_size,
                              hipStream_t stream) {
    const float* x    = (const float*)d_in[0];
    const float* k1   = (const float*)d_in[1];
    const float* k2   = (const float*)d_in[2];
    const float* bias = (const float*)d_in[3];
    float* out = (float*)d_out;

    const int nblocks = BB * (HO / 4) * FG;  // 16 * 16 * 4 = 1024
    morph_kernel<<<dim3(nblocks), dim3(256), 0, stream>>>(x, k1, k2, bias, out);
}

// Round 2
// 19.725 us; speedup vs baseline: 2.0195x; 2.0195x over previous
//
#include <hip/hip_runtime.h>
#include <math.h>

// MorphLayer via max-product identity:
//   exp(max_k(log(max(±x,eps)) + w_k)) = max_k( max(±x,eps) * exp(w_k) )
// out = M(xp,e1) - M(xp,e2) - M(xn,e1) + M(xn,e2) + bias
// x: (16,3,66,66) f32, k1/k2: (27,32) f32, bias: (32,), out: (16,32,64,64) f32

#define BB 16
#define CC 3
#define HH 66
#define WW 66
#define HO 64
#define WO 64
#define FF 32
#define KK 27
#define FPG 4              // filters per block
#define FG (FF / FPG)      // 8 filter groups
#define EPS 1e-12f

// prep: ws[0..863] = exp(k1), ws[864..1727] = exp(k2)
__global__ void morph_prep(const float* __restrict__ k1,
                           const float* __restrict__ k2,
                           float* __restrict__ ws) {
    int i = threadIdx.x + blockIdx.x * blockDim.x;
    if (i < KK * FF) {
        ws[i]           = expf(k1[i]);
        ws[KK * FF + i] = expf(k2[i]);
    }
}

__global__ __launch_bounds__(256, 8)
void morph_main(const float* __restrict__ x,
                const float* __restrict__ ew,   // [2][27][32] exp-weights
                const float* __restrict__ bias,
                float* __restrict__ out) {
    const int tid = threadIdx.x;
    const int wo = tid & 63;        // 0..63
    const int r  = tid >> 6;        // 0..3 (row within block)
    int bid = blockIdx.x;
    const int fg = bid & (FG - 1);  bid >>= 3;   // filter group 0..7
    const int rg = bid & 15;        bid >>= 4;   // row group 0..15
    const int b  = bid;                          // batch 0..15
    const int ho = rg * 4 + r;
    const int f0 = fg * FPG;

    float m11[FPG], m12[FPG], m21[FPG], m22[FPG];
    #pragma unroll
    for (int ff = 0; ff < FPG; ++ff) {
        m11[ff] = 0.f; m12[ff] = 0.f; m21[ff] = 0.f; m22[ff] = 0.f;
    }

    const float* xb  = x + ((size_t)b * CC * HH * WW);
    const float* ew1 = ew + f0;
    const float* ew2 = ew + KK * FF + f0;

    #pragma unroll
    for (int c = 0; c < CC; ++c) {
        #pragma unroll
        for (int di = 0; di < 3; ++di) {
            #pragma unroll
            for (int dj = 0; dj < 3; ++dj) {
                const int k = c * 9 + di * 3 + dj;
                const float v = xb[(c * HH + (ho + di)) * WW + (wo + dj)];
                const float xp = fmaxf(v, EPS);
                const float xn = fmaxf(-v, EPS);
                #pragma unroll
                for (int ff = 0; ff < FPG; ++ff) {
                    const float e1 = ew1[k * FF + ff];  // wave-uniform -> s_load
                    const float e2 = ew2[k * FF + ff];
                    m11[ff] = fmaxf(m11[ff], xp * e1);
                    m12[ff] = fmaxf(m12[ff], xp * e2);
                    m21[ff] = fmaxf(m21[ff], xn * e1);
                    m22[ff] = fmaxf(m22[ff], xn * e2);
                }
            }
        }
    }

    #pragma unroll
    for (int ff = 0; ff < FPG; ++ff) {
        const float res = m11[ff] - m12[ff] - m21[ff] + m22[ff] + bias[f0 + ff];
        out[(((size_t)b * FF + (f0 + ff)) * HO + ho) * WO + wo] = res;
    }
}

extern "C" void kernel_launch(void* const* d_in, const int* in_sizes, int n_in,
                              void* d_out, int out_size, void* d_ws, size_t ws_size,
                              hipStream_t stream) {
    const float* x    = (const float*)d_in[0];
    const float* k1   = (const float*)d_in[1];
    const float* k2   = (const float*)d_in[2];
    const float* bias = (const float*)d_in[3];
    float* out = (float*)d_out;
    float* ew  = (float*)d_ws;   // needs 2*27*32*4 = 6912 bytes

    morph_prep<<<dim3((KK * FF + 255) / 256), dim3(256), 0, stream>>>(k1, k2, ew);

    const int nblocks = BB * (HO / 4) * FG;  // 16 * 16 * 8 = 2048
    morph_main<<<dim3(nblocks), dim3(256), 0, stream>>>(x, ew, bias, out);
}

// Round 3
// 15.263 us; speedup vs baseline: 2.6098x; 1.2923x over previous
//
#include <hip/hip_runtime.h>
#include <math.h>

// MorphLayer via max-product identity (exp is monotone, exp∘log∘clamp = clamp):
//   exp(max_k(log(max(±x,eps)) + w_k)) = max_k( max(±x,eps) * exp(w_k) )
// out = M(xp,e1) - M(xp,e2) - M(xn,e1) + M(xn,e2) + bias
// Single fused kernel: per-block exp(weights)->LDS, pre-clamped x->LDS.

#define BB 16
#define CC 3
#define HH 66
#define WW 66
#define HO 64
#define WO 64
#define FF 32
#define KK 27
#define FPG 4              // filters per block
#define FG (FF / FPG)      // 8 filter groups
#define ROWS 4             // output rows per block
#define IR (ROWS + 2)      // staged input rows
#define EPS 1e-12f

__global__ __launch_bounds__(256, 8)
void morph_fused(const float* __restrict__ x,
                 const float* __restrict__ k1,
                 const float* __restrict__ k2,
                 const float* __restrict__ bias,
                 float* __restrict__ out) {
    __shared__ float xs[CC * IR * WW * 2];  // (xp,xn) interleaved, 9504 B
    __shared__ float wl[KK * 8];            // [k][e1 x4 | e2 x4], 864 B

    const int tid = threadIdx.x;
    int bid = blockIdx.x;
    const int fg = bid & (FG - 1); bid >>= 3;  // filter group 0..7
    const int rg = bid & 15;       bid >>= 4;  // row group 0..15
    const int b  = bid;                        // batch
    const int f0 = fg * FPG;
    const int ho0 = rg * ROWS;

    // ---- stage exp(weights) for this block's 4 filters ----
    if (tid < KK * 8) {
        const int k = tid >> 3;
        const int j = tid & 3;
        const int h = (tid >> 2) & 1;
        const float w = h ? k2[k * FF + f0 + j] : k1[k * FF + f0 + j];
        wl[tid] = expf(w);
    }
    // ---- stage x window, pre-clamped both signs ----
    const float* xb = x + (size_t)b * CC * HH * WW;
    for (int i = tid; i < CC * IR * WW; i += 256) {
        const int c   = i / (IR * WW);
        const int rem = i - c * (IR * WW);
        const int row = rem / WW;
        const int col = rem - row * WW;
        const float v = xb[(c * HH + ho0 + row) * WW + col];
        xs[i * 2 + 0] = fmaxf(v, EPS);
        xs[i * 2 + 1] = fmaxf(-v, EPS);
    }
    __syncthreads();

    const int wo = tid & 63;
    const int r  = tid >> 6;
    const int ho = ho0 + r;

    float m11x = 0.f, m11y = 0.f, m11z = 0.f, m11w = 0.f;
    float m12x = 0.f, m12y = 0.f, m12z = 0.f, m12w = 0.f;
    float m21x = 0.f, m21y = 0.f, m21z = 0.f, m21w = 0.f;
    float m22x = 0.f, m22y = 0.f, m22z = 0.f, m22w = 0.f;

    const float2* xs2 = (const float2*)xs;
    const float4* wl4 = (const float4*)wl;

    #pragma unroll
    for (int c = 0; c < CC; ++c) {
        #pragma unroll
        for (int di = 0; di < 3; ++di) {
            #pragma unroll
            for (int dj = 0; dj < 3; ++dj) {
                const int k = c * 9 + di * 3 + dj;
                const float2 xv = xs2[(c * IR + r + di) * WW + wo + dj];
                const float4 e1 = wl4[k * 2];
                const float4 e2 = wl4[k * 2 + 1];
#define UPD(comp) \
                m11##comp = fmaxf(m11##comp, xv.x * e1.comp); \
                m12##comp = fmaxf(m12##comp, xv.x * e2.comp); \
                m21##comp = fmaxf(m21##comp, xv.y * e1.comp); \
                m22##comp = fmaxf(m22##comp, xv.y * e2.comp);
                UPD(x) UPD(y) UPD(z) UPD(w)
#undef UPD
            }
        }
    }

    const size_t obase = ((size_t)b * FF + f0) * (HO * WO) + (size_t)ho * WO + wo;
    out[obase + 0 * HO * WO] = m11x - m12x - m21x + m22x + bias[f0 + 0];
    out[obase + 1 * HO * WO] = m11y - m12y - m21y + m22y + bias[f0 + 1];
    out[obase + 2 * HO * WO] = m11z - m12z - m21z + m22z + bias[f0 + 2];
    out[obase + 3 * HO * WO] = m11w - m12w - m21w + m22w + bias[f0 + 3];
}

extern "C" void kernel_launch(void* const* d_in, const int* in_sizes, int n_in,
                              void* d_out, int out_size, void* d_ws, size_t ws_size,
                              hipStream_t stream) {
    const float* x    = (const float*)d_in[0];
    const float* k1   = (const float*)d_in[1];
    const float* k2   = (const float*)d_in[2];
    const float* bias = (const float*)d_in[3];
    float* out = (float*)d_out;

    const int nblocks = BB * (HO / ROWS) * FG;  // 16 * 16 * 8 = 2048
    morph_fused<<<dim3(nblocks), dim3(256), 0, stream>>>(x, k1, k2, bias, out);
}

// Round 4
// 13.876 us; speedup vs baseline: 2.8707x; 1.1000x over previous
//
#include <hip/hip_runtime.h>
#include <math.h>

// MorphLayer via max-product identity (exp is monotone, exp∘log∘clamp = clamp):
//   exp(max_k(log(max(±x,eps)) + w_k)) = max_k( max(±x,eps) * exp(w_k) )
// plus the negation identity:
//   max(-v,eps)*e = max(-(v*e), eps*e)  -> reuse p = v*e with free neg modifier;
//   eps*e ~ 1e-12 contributes <=1e-12 to out (threshold 5e-2) -> init chains at 0.
// out = M11 - M12 - M21 + M22 + bias
// x: (16,3,66,66) f32, k1/k2: (27,32) f32, bias: (32,), out: (16,32,64,64) f32

#define BB 16
#define CC 3
#define HH 66
#define WW 66
#define HO 64
#define WO 64
#define FF 32
#define KK 27
#define FPG 4              // filters per block
#define FG (FF / FPG)      // 8 filter groups
#define ROWS 4             // output rows per block
#define IR (ROWS + 2)      // staged input rows

typedef float f32x2 __attribute__((ext_vector_type(2)));

__global__ __launch_bounds__(256, 8)
void morph_fused(const float* __restrict__ x,
                 const float* __restrict__ k1,
                 const float* __restrict__ k2,
                 const float* __restrict__ bias,
                 float* __restrict__ out) {
    __shared__ float xs[CC * IR * WW];   // raw x window, 4752 B
    __shared__ float wl[KK * 8];         // [k][e1 x4 | e2 x4], 864 B

    const int tid = threadIdx.x;
    int bid = blockIdx.x;
    const int fg = bid & (FG - 1); bid >>= 3;  // filter group 0..7
    const int rg = bid & 15;       bid >>= 4;  // row group 0..15
    const int b  = bid;                        // batch
    const int f0 = fg * FPG;
    const int ho0 = rg * ROWS;

    // ---- stage exp(weights) for this block's 4 filters ----
    if (tid < KK * 8) {
        const int k = tid >> 3;
        const int j = tid & 3;
        const int h = (tid >> 2) & 1;
        const float w = h ? k2[k * FF + f0 + j] : k1[k * FF + f0 + j];
        wl[tid] = expf(w);
    }
    // ---- stage raw x window (no clamps needed) ----
    const float* xb = x + (size_t)b * CC * HH * WW;
    for (int i = tid; i < CC * IR * WW; i += 256) {
        const int c   = i / (IR * WW);
        const int rem = i - c * (IR * WW);
        const int row = rem / WW;
        const int col = rem - row * WW;
        xs[i] = xb[(c * HH + ho0 + row) * WW + col];
    }
    __syncthreads();

    const int wo = tid & 63;
    const int r  = tid >> 6;
    const int ho = ho0 + r;

    // 16 accumulators; m21/m22 chains consume negated products (free modifier)
    float m11x = 0.f, m11y = 0.f, m11z = 0.f, m11w = 0.f;
    float m12x = 0.f, m12y = 0.f, m12z = 0.f, m12w = 0.f;
    float m21x = 0.f, m21y = 0.f, m21z = 0.f, m21w = 0.f;
    float m22x = 0.f, m22y = 0.f, m22z = 0.f, m22w = 0.f;

    const f32x2* wl2 = (const f32x2*)wl;

    #pragma unroll
    for (int c = 0; c < CC; ++c) {
        #pragma unroll
        for (int di = 0; di < 3; ++di) {
            #pragma unroll
            for (int dj = 0; dj < 3; ++dj) {
                const int k = c * 9 + di * 3 + dj;
                const float v = xs[(c * IR + r + di) * WW + wo + dj];
                const f32x2 vv = {v, v};
                // products via packed f32 mul (v_pk_mul_f32)
                const f32x2 p1a = vv * wl2[k * 4 + 0];   // v*e1.xy
                const f32x2 p1b = vv * wl2[k * 4 + 1];   // v*e1.zw
                const f32x2 p2a = vv * wl2[k * 4 + 2];   // v*e2.xy
                const f32x2 p2b = vv * wl2[k * 4 + 3];   // v*e2.zw
                m11x = fmaxf(m11x, p1a.x);  m11y = fmaxf(m11y, p1a.y);
                m11z = fmaxf(m11z, p1b.x);  m11w = fmaxf(m11w, p1b.y);
                m12x = fmaxf(m12x, p2a.x);  m12y = fmaxf(m12y, p2a.y);
                m12z = fmaxf(m12z, p2b.x);  m12w = fmaxf(m12w, p2b.y);
                m21x = fmaxf(m21x, -p1a.x); m21y = fmaxf(m21y, -p1a.y);
                m21z = fmaxf(m21z, -p1b.x); m21w = fmaxf(m21w, -p1b.y);
                m22x = fmaxf(m22x, -p2a.x); m22y = fmaxf(m22y, -p2a.y);
                m22z = fmaxf(m22z, -p2b.x); m22w = fmaxf(m22w, -p2b.y);
            }
        }
    }

    const size_t obase = ((size_t)b * FF + f0) * (HO * WO) + (size_t)ho * WO + wo;
    out[obase + 0 * HO * WO] = m11x - m12x - m21x + m22x + bias[f0 + 0];
    out[obase + 1 * HO * WO] = m11y - m12y - m21y + m22y + bias[f0 + 1];
    out[obase + 2 * HO * WO] = m11z - m12z - m21z + m22z + bias[f0 + 2];
    out[obase + 3 * HO * WO] = m11w - m12w - m21w + m22w + bias[f0 + 3];
}

extern "C" void kernel_launch(void* const* d_in, const int* in_sizes, int n_in,
                              void* d_out, int out_size, void* d_ws, size_t ws_size,
                              hipStream_t stream) {
    const float* x    = (const float*)d_in[0];
    const float* k1   = (const float*)d_in[1];
    const float* k2   = (const float*)d_in[2];
    const float* bias = (const float*)d_in[3];
    float* out = (float*)d_out;

    const int nblocks = BB * (HO / ROWS) * FG;  // 16 * 16 * 8 = 2048
    morph_fused<<<dim3(nblocks), dim3(256), 0, stream>>>(x, k1, k2, bias, out);
}